// Round 3
// baseline (139.851 us; speedup 1.0000x reference)
//
#include <hip/hip_runtime.h>

#define DPROJ 1024

typedef short  bf16x8 __attribute__((ext_vector_type(8)));
typedef float  f32x4  __attribute__((ext_vector_type(4)));
typedef unsigned short u16x4 __attribute__((ext_vector_type(4)));

__device__ __forceinline__ unsigned short f2bf(float f) {
  unsigned u = __builtin_bit_cast(unsigned, f);
  u += 0x7FFFu + ((u >> 16) & 1u);          // round-to-nearest-even
  return (unsigned short)(u >> 16);
}

// ---------------------------------------------------------------------------
// Kernel 1: classify tokens into 4 bucket lists. Entry packs (in-bucket row
// << 14) | token_id so the GEMM never has to gather inp[] again.
// Wave-aggregated atomics: one atomicAdd per (wave,bucket). List order is
// nondeterministic but each token's output is position-independent.
// ---------------------------------------------------------------------------
__global__ __launch_bounds__(256) void classify_kernel(const int* __restrict__ inp, int n,
                                                       int* __restrict__ counts,
                                                       unsigned* __restrict__ lists) {
  int t = blockIdx.x * 256 + threadIdx.x;
  int lane = threadIdx.x & 63;
  int v = (t < n) ? inp[t] : -1;
  int b = (v < 0) ? -1 : (v >= 200000) ? 3 : (v >= 40000) ? 2 : (v >= 20000) ? 1 : 0;
  int lo = (b == 3) ? 200000 : (b == 2) ? 40000 : (b == 1) ? 20000 : 0;
#pragma unroll
  for (int i = 0; i < 4; ++i) {
    unsigned long long m = __ballot(b == i);
    if (b == i) {
      int rank = __popcll(m & ((1ull << lane) - 1ull));
      int src  = __ffsll((unsigned long long)m) - 1;
      int base = 0;
      if (lane == src) base = atomicAdd(&counts[i], __popcll(m));
      base = __shfl(base, src);
      lists[i * n + base + rank] = ((unsigned)(v - lo) << 14) | (unsigned)t;
    }
  }
}

// ---------------------------------------------------------------------------
// Kernel 2: per-bucket GEMM on bf16 MFMA (16x16x32, fp32 accum).
// Block = 256 thr (4 waves, 2x2), tile = 64 tokens x 256 cols, K-chunk = 64.
// LDS bf16 tiles with XOR swizzle byte ^= (row&7)<<4 (128B rows, per G4).
// Epilogue: per-wave LDS transpose -> float4 stores (256B row segments).
// ---------------------------------------------------------------------------
template <int D>
__device__ __forceinline__ void gemm_body(const float* __restrict__ emb,
                                          const float* __restrict__ proj,
                                          const unsigned* __restrict__ list,
                                          int cnt, int r0,
                                          float* __restrict__ out, char* smem) {
  constexpr int CH = (D + 63) / 64;        // K-chunks: 16,4,1,1
  constexpr int KR = (D < 64) ? D : 64;    // real k per chunk (zero-pad rest)
  const int c0   = blockIdx.x * 256;
  const int tid  = threadIdx.x;
  const int lane = tid & 63;
  const int w    = tid >> 6;               // wave 0..3
  const int wr   = w >> 1, wc = w & 1;     // 2x2 wave grid: 32 rows x 128 cols each
  const int lr   = lane & 15, t16 = lane >> 4;

  char* Ab = smem;                          // A: 64 rows x 128 B (bf16)  =  8 KB
  char* Bb = smem + 8192;                   // B: 256 rows x 128 B (bf16) = 32 KB
  unsigned* toks = (unsigned*)(smem + 40960);  // 64 packed entries

  if (tid < 64) {
    int p = r0 + tid;
    toks[tid] = (p < cnt) ? list[p] : 0u;   // pads -> row 0 (their stores suppressed)
  }
  __syncthreads();

  f32x4 acc[2][8];
#pragma unroll
  for (int fi = 0; fi < 2; ++fi)
#pragma unroll
    for (int fj = 0; fj < 8; ++fj) acc[fi][fj] = (f32x4){0.f, 0.f, 0.f, 0.f};

  for (int ch = 0; ch < CH; ++ch) {
    const int k0 = ch * 64;
    // ---- stage A: 64 rows x 64 k (1024 float4-quads), fp32->bf16, swizzled
#pragma unroll
    for (int i = 0; i < 4; ++i) {
      int q = tid + i * 256;
      int r = q >> 4, c4 = (q & 15) * 4;
      float4 v = make_float4(0.f, 0.f, 0.f, 0.f);
      if (KR == 64 || c4 < KR)
        v = *reinterpret_cast<const float4*>(emb + (size_t)(toks[r] >> 14) * D + k0 + c4);
      u16x4 o = {f2bf(v.x), f2bf(v.y), f2bf(v.z), f2bf(v.w)};
      *reinterpret_cast<u16x4*>(Ab + r * 128 + ((c4 * 2) ^ ((r & 7) << 4))) = o;
    }
    // ---- stage B: 256 cols x 64 k (4096 quads)
#pragma unroll
    for (int i = 0; i < 16; ++i) {
      int q = tid + i * 256;
      int c = q >> 4, c4 = (q & 15) * 4;
      float4 v = make_float4(0.f, 0.f, 0.f, 0.f);
      if (KR == 64 || c4 < KR)
        v = *reinterpret_cast<const float4*>(proj + (size_t)(c0 + c) * D + k0 + c4);
      u16x4 o = {f2bf(v.x), f2bf(v.y), f2bf(v.z), f2bf(v.w)};
      *reinterpret_cast<u16x4*>(Bb + c * 128 + ((c4 * 2) ^ ((c & 7) << 4))) = o;
    }
    __syncthreads();

#pragma unroll
    for (int s = 0; s < 2; ++s) {           // two K=32 MFMA steps per chunk
      bf16x8 a[2], b[8];
#pragma unroll
      for (int fi = 0; fi < 2; ++fi) {
        int row = wr * 32 + fi * 16 + lr;
        a[fi] = *reinterpret_cast<const bf16x8*>(
            Ab + row * 128 + ((s * 64 + t16 * 16) ^ ((row & 7) << 4)));
      }
#pragma unroll
      for (int fj = 0; fj < 8; ++fj) {
        int col = wc * 128 + fj * 16 + lr;
        b[fj] = *reinterpret_cast<const bf16x8*>(
            Bb + col * 128 + ((s * 64 + t16 * 16) ^ ((col & 7) << 4)));
      }
#pragma unroll
      for (int fi = 0; fi < 2; ++fi)
#pragma unroll
        for (int fj = 0; fj < 8; ++fj)
          acc[fi][fj] = __builtin_amdgcn_mfma_f32_16x16x32_bf16(a[fi], b[fj], acc[fi][fj], 0, 0, 0);
    }
    __syncthreads();   // also guards the epilogue's LDS reuse on the last chunk
  }

  // ---- epilogue: per-wave transpose through LDS, then float4 row-segment
  // stores (16 lanes cover 256 B contiguous). C/D frag layout: col = lane&15,
  // row = (lane>>4)*4 + reg (HW-verified).
  float* T = reinterpret_cast<float*>(smem + w * 8704);  // 32 rows x stride 68
#pragma unroll
  for (int h = 0; h < 2; ++h) {            // two 64-col halves of the wave's 128
#pragma unroll
    for (int fi = 0; fi < 2; ++fi)
#pragma unroll
      for (int j = 0; j < 4; ++j) {
        int fj = h * 4 + j;
#pragma unroll
        for (int reg = 0; reg < 4; ++reg)
          T[(fi * 16 + t16 * 4 + reg) * 68 + j * 16 + lr] = acc[fi][fj][reg];
      }
    // same-wave ds_write -> ds_read: compiler inserts lgkmcnt ordering
#pragma unroll
    for (int j = 0; j < 8; ++j) {
      int row = j * 4 + t16;               // 0..31 within wave
      int p   = wr * 32 + row;             // row within 64-row tile
      if (r0 + p < cnt) {
        unsigned e = toks[p];
        float4 v = *reinterpret_cast<const float4*>(&T[row * 68 + lr * 4]);
        *reinterpret_cast<float4*>(out + (size_t)(e & 16383u) * DPROJ +
                                   c0 + wc * 128 + h * 64 + lr * 4) = v;
      }
    }
  }
}

__global__ __launch_bounds__(256) void gemm_all(
    const float* __restrict__ e0, const float* __restrict__ p0,
    const float* __restrict__ e1, const float* __restrict__ p1,
    const float* __restrict__ e2, const float* __restrict__ p2,
    const float* __restrict__ e3, const float* __restrict__ p3,
    const int* __restrict__ counts, const unsigned* __restrict__ lists,
    float* __restrict__ out, int n) {
  extern __shared__ char smem[];
  int4 c = *reinterpret_cast<const int4*>(counts);
  int t0 = (c.x + 63) >> 6, t1 = (c.y + 63) >> 6,
      t2 = (c.z + 63) >> 6, t3 = (c.w + 63) >> 6;
  int y = blockIdx.y;
  int b, r, cnt;
  if      (y < t0)                { b = 0; r = y;                cnt = c.x; }
  else if (y < t0 + t1)           { b = 1; r = y - t0;           cnt = c.y; }
  else if (y < t0 + t1 + t2)      { b = 2; r = y - t0 - t1;      cnt = c.z; }
  else if (y < t0 + t1 + t2 + t3) { b = 3; r = y - t0 - t1 - t2; cnt = c.w; }
  else return;
  int r0 = r * 64;
  switch (b) {
    case 0: gemm_body<1024>(e0, p0, lists + (size_t)0 * n, cnt, r0, out, smem); break;
    case 1: gemm_body< 256>(e1, p1, lists + (size_t)1 * n, cnt, r0, out, smem); break;
    case 2: gemm_body<  64>(e2, p2, lists + (size_t)2 * n, cnt, r0, out, smem); break;
    case 3: gemm_body<  16>(e3, p3, lists + (size_t)3 * n, cnt, r0, out, smem); break;
  }
}

// ---------------------------------------------------------------------------
// Input order (setup_inputs dict order): inp, emb0, proj0, ... NO — the setup
// loop assigns emb{i} for i=0..3 first? It assigns out["emb{i}"] then
// out["proj{i}"] within the same iteration -> inp, emb0, proj0, emb1, proj1,
// emb2, proj2, emb3, proj3. (Verified by round-1/2 passes.)
// ---------------------------------------------------------------------------
extern "C" void kernel_launch(void* const* d_in, const int* in_sizes, int n_in,
                              void* d_out, int out_size, void* d_ws, size_t ws_size,
                              hipStream_t stream) {
  const int*   inp   = (const int*)d_in[0];
  const float* emb0  = (const float*)d_in[1];
  const float* proj0 = (const float*)d_in[2];
  const float* emb1  = (const float*)d_in[3];
  const float* proj1 = (const float*)d_in[4];
  const float* emb2  = (const float*)d_in[5];
  const float* proj2 = (const float*)d_in[6];
  const float* emb3  = (const float*)d_in[7];
  const float* proj3 = (const float*)d_in[8];
  float* out = (float*)d_out;
  const int n = in_sizes[0];  // 16384 tokens

  int*      counts = (int*)d_ws;                 // 4 ints
  unsigned* lists  = (unsigned*)d_ws + 4;        // 4 x n packed entries

  hipMemsetAsync(counts, 0, 4 * sizeof(int), stream);
  classify_kernel<<<dim3((n + 255) / 256), dim3(256), 0, stream>>>(inp, n, counts, lists);

  // y covers worst-case total row-tiles: sum_i ceil(cnt_i/64) <= n/64 + 3 = 259
  dim3 grid(DPROJ / 256, (n + 63) / 64 + 3, 1);
  size_t smem_bytes = 40960 + 64 * sizeof(unsigned);  // 41216 B -> 3 blocks/CU
  gemm_all<<<grid, dim3(256), smem_bytes, stream>>>(emb0, proj0, emb1, proj1,
                                                    emb2, proj2, emb3, proj3,
                                                    counts, lists, out, n);
}

// Round 4
// 66.500 us; speedup vs baseline: 2.1030x; 2.1030x over previous
//
#include <hip/hip_runtime.h>

#define DPROJ 1024

typedef short  bf16x8 __attribute__((ext_vector_type(8)));
typedef float  f32x4  __attribute__((ext_vector_type(4)));
typedef unsigned short u16x4 __attribute__((ext_vector_type(4)));

__device__ __forceinline__ unsigned short f2bf(float f) {
  unsigned u = __builtin_bit_cast(unsigned, f);
  u += 0x7FFFu + ((u >> 16) & 1u);          // round-to-nearest-even
  return (unsigned short)(u >> 16);
}

// ---------------------------------------------------------------------------
// Kernel 1: classify tokens into 4 bucket lists. Entry packs (in-bucket row
// << 14) | token_id. Wave-aggregated atomics. List order nondeterministic but
// each token's output value is position-independent.
// ---------------------------------------------------------------------------
__global__ __launch_bounds__(256) void classify_kernel(const int* __restrict__ inp, int n,
                                                       int* __restrict__ counts,
                                                       unsigned* __restrict__ lists) {
  int t = blockIdx.x * 256 + threadIdx.x;
  int lane = threadIdx.x & 63;
  int v = (t < n) ? inp[t] : -1;
  int b = (v < 0) ? -1 : (v >= 200000) ? 3 : (v >= 40000) ? 2 : (v >= 20000) ? 1 : 0;
  int lo = (b == 3) ? 200000 : (b == 2) ? 40000 : (b == 1) ? 20000 : 0;
#pragma unroll
  for (int i = 0; i < 4; ++i) {
    unsigned long long m = __ballot(b == i);
    if (b == i) {
      int rank = __popcll(m & ((1ull << lane) - 1ull));
      int src  = __ffsll((unsigned long long)m) - 1;
      int base = 0;
      if (lane == src) base = atomicAdd(&counts[i], __popcll(m));
      base = __shfl(base, src);
      lists[i * n + base + rank] = ((unsigned)(v - lo) << 14) | (unsigned)t;
    }
  }
}

// ---------------------------------------------------------------------------
// Kernel 1b: zero the output rows of bucket-0 tokens (split-K blocks then
// accumulate into them with atomics). ~1224 rows x 4 KB expected.
// ---------------------------------------------------------------------------
__global__ __launch_bounds__(256) void zero_b0(const int* __restrict__ counts,
                                               const unsigned* __restrict__ list0,
                                               float* __restrict__ out) {
  int total = counts[0] * 256;            // float4 segments, 256 per row
  for (int i = blockIdx.x * 256 + threadIdx.x; i < total; i += gridDim.x * 256) {
    int p = i >> 8, seg = i & 255;
    unsigned tok = list0[p] & 16383u;
    *reinterpret_cast<float4*>(out + (size_t)tok * DPROJ + seg * 4) =
        make_float4(0.f, 0.f, 0.f, 0.f);
  }
}

// ---------------------------------------------------------------------------
// Kernel 2: balanced per-bucket GEMM, bf16 MFMA 16x16x32, fp32 accum.
// Block = 256 thr (4 waves 2x2), tile = 64 rows x 128 cols, <=4 K-chunks of
// 64. Bucket 0 runs KZ=4 split-K with fp32 atomic accumulate. LDS bf16 tiles
// XOR-swizzled byte ^= (row&7)<<4 (G4: 128B rows else 16-way conflict).
// ---------------------------------------------------------------------------
template <int D, int KZ, bool ATOMIC>
__device__ __forceinline__ void gemm_body(const float* __restrict__ emb,
                                          const float* __restrict__ proj,
                                          const unsigned* __restrict__ list,
                                          int cnt, int r0, int kz,
                                          float* __restrict__ out, char* smem) {
  constexpr int KTOT = (D + 63) / 64;      // 64-wide chunks total
  constexpr int CHB  = KTOT / KZ;          // chunks per block (<= 4)
  constexpr int KR   = (D < 64) ? D : 64;  // real k per chunk (zero-pad rest)
  const int c0   = blockIdx.x * 128;
  const int tid  = threadIdx.x;
  const int lane = tid & 63;
  const int w    = tid >> 6;
  const int wr   = w >> 1, wc = w & 1;     // 2x2 wave grid: 32 rows x 64 cols
  const int lr   = lane & 15, t16 = lane >> 4;

  char* Ab = smem;                          // A: 64 x 128 B  =  8 KB
  char* Bb = smem + 8192;                   // B: 128 x 128 B = 16 KB
  unsigned* toks = (unsigned*)(smem + 24576);

  if (tid < 64) {
    int p = r0 + tid;
    toks[tid] = (p < cnt) ? list[p] : 0u;   // pads -> row 0 (stores suppressed)
  }
  __syncthreads();

  f32x4 acc[2][4];
#pragma unroll
  for (int fi = 0; fi < 2; ++fi)
#pragma unroll
    for (int fj = 0; fj < 4; ++fj) acc[fi][fj] = (f32x4){0.f, 0.f, 0.f, 0.f};

  for (int ch = 0; ch < CHB; ++ch) {
    const int k0 = (kz * CHB + ch) * 64;
    // ---- stage A: 64 rows x 64 k = 1024 quads (4/thread), fp32->bf16
#pragma unroll
    for (int i = 0; i < 4; ++i) {
      int q = tid + i * 256;
      int r = q >> 4, c4 = (q & 15) * 4;
      float4 v = make_float4(0.f, 0.f, 0.f, 0.f);
      if (KR == 64 || c4 < KR)
        v = *reinterpret_cast<const float4*>(emb + (size_t)(toks[r] >> 14) * D + k0 + c4);
      u16x4 o = {f2bf(v.x), f2bf(v.y), f2bf(v.z), f2bf(v.w)};
      *reinterpret_cast<u16x4*>(Ab + r * 128 + ((c4 * 2) ^ ((r & 7) << 4))) = o;
    }
    // ---- stage B: 128 cols x 64 k = 2048 quads (8/thread)
#pragma unroll
    for (int i = 0; i < 8; ++i) {
      int q = tid + i * 256;
      int c = q >> 4, c4 = (q & 15) * 4;
      float4 v = make_float4(0.f, 0.f, 0.f, 0.f);
      if (KR == 64 || c4 < KR)
        v = *reinterpret_cast<const float4*>(proj + (size_t)(c0 + c) * D + k0 + c4);
      u16x4 o = {f2bf(v.x), f2bf(v.y), f2bf(v.z), f2bf(v.w)};
      *reinterpret_cast<u16x4*>(Bb + c * 128 + ((c4 * 2) ^ ((c & 7) << 4))) = o;
    }
    __syncthreads();

#pragma unroll
    for (int s = 0; s < 2; ++s) {           // two K=32 MFMA steps
      bf16x8 a[2], b[4];
#pragma unroll
      for (int fi = 0; fi < 2; ++fi) {
        int row = wr * 32 + fi * 16 + lr;
        a[fi] = *reinterpret_cast<const bf16x8*>(
            Ab + row * 128 + ((s * 64 + t16 * 16) ^ ((row & 7) << 4)));
      }
#pragma unroll
      for (int fj = 0; fj < 4; ++fj) {
        int col = wc * 64 + fj * 16 + lr;
        b[fj] = *reinterpret_cast<const bf16x8*>(
            Bb + col * 128 + ((s * 64 + t16 * 16) ^ ((col & 7) << 4)));
      }
#pragma unroll
      for (int fi = 0; fi < 2; ++fi)
#pragma unroll
        for (int fj = 0; fj < 4; ++fj)
          acc[fi][fj] = __builtin_amdgcn_mfma_f32_16x16x32_bf16(a[fi], b[fj], acc[fi][fj], 0, 0, 0);
    }
    __syncthreads();   // also makes LDS safe for epilogue reuse
  }

  if (ATOMIC) {
    // split-K accumulate: hardware fp32 atomic add; 16 lanes (lr) form 64 B
    // contiguous bursts. Rounding order varies ~1e-7 << threshold.
#pragma unroll
    for (int fi = 0; fi < 2; ++fi)
#pragma unroll
      for (int reg = 0; reg < 4; ++reg) {
        int p = wr * 32 + fi * 16 + t16 * 4 + reg;
        if (r0 + p < cnt) {
          float* base = out + (size_t)(toks[p] & 16383u) * DPROJ + c0 + wc * 64 + lr;
#pragma unroll
          for (int fj = 0; fj < 4; ++fj)
            unsafeAtomicAdd(base + fj * 16, acc[fi][fj][reg]);
        }
      }
  } else {
    // transpose 16 rows x 64 cols per pass through per-wave LDS (reuses A/B
    // region; quarter-wave = one T row on both sides -> conflict-free),
    // then float4 stores (256 B contiguous per quarter-wave).
    float* T = reinterpret_cast<float*>(smem + w * 4352);  // 16 x stride 68
#pragma unroll
    for (int fi = 0; fi < 2; ++fi) {
#pragma unroll
      for (int fj = 0; fj < 4; ++fj)
#pragma unroll
        for (int reg = 0; reg < 4; ++reg)
          T[(t16 * 4 + reg) * 68 + fj * 16 + lr] = acc[fi][fj][reg];
      // same-wave ds_write->ds_read ordering handled by compiler lgkmcnt
#pragma unroll
      for (int rr = 0; rr < 4; ++rr) {
        int p = wr * 32 + fi * 16 + rr * 4 + t16;
        if (r0 + p < cnt) {
          float4 v = *reinterpret_cast<const float4*>(&T[(rr * 4 + t16) * 68 + lr * 4]);
          *reinterpret_cast<float4*>(out + (size_t)(toks[p] & 16383u) * DPROJ +
                                     c0 + wc * 64 + lr * 4) = v;
        }
      }
    }
  }
}

__global__ __launch_bounds__(256) void gemm_all(
    const float* __restrict__ e0, const float* __restrict__ p0,
    const float* __restrict__ e1, const float* __restrict__ p1,
    const float* __restrict__ e2, const float* __restrict__ p2,
    const float* __restrict__ e3, const float* __restrict__ p3,
    const int* __restrict__ counts, const unsigned* __restrict__ lists,
    float* __restrict__ out, int n) {
  extern __shared__ char smem[];
  int4 c = *reinterpret_cast<const int4*>(counts);
  int t0 = ((c.x + 63) >> 6) << 2;   // bucket-0 tiles x 4 kz splits
  int t1 = (c.y + 63) >> 6, t2 = (c.z + 63) >> 6, t3 = (c.w + 63) >> 6;
  int y = blockIdx.y;
  if (y < t0) {                       // heavy blocks dispatch first
    gemm_body<1024, 4, true>(e0, p0, lists, c.x, (y >> 2) * 64, y & 3, out, smem);
    return;
  }
  y -= t0;
  if (y < t1) { gemm_body<256, 1, false>(e1, p1, lists + (size_t)n,     c.y, y * 64, 0, out, smem); return; }
  y -= t1;
  if (y < t2) { gemm_body< 64, 1, false>(e2, p2, lists + (size_t)2 * n, c.z, y * 64, 0, out, smem); return; }
  y -= t2;
  if (y < t3) { gemm_body< 16, 1, false>(e3, p3, lists + (size_t)3 * n, c.w, y * 64, 0, out, smem); return; }
}

// ---------------------------------------------------------------------------
// Input order (setup_inputs dict order, verified rounds 1-3):
// inp, emb0, proj0, emb1, proj1, emb2, proj2, emb3, proj3.
// ---------------------------------------------------------------------------
extern "C" void kernel_launch(void* const* d_in, const int* in_sizes, int n_in,
                              void* d_out, int out_size, void* d_ws, size_t ws_size,
                              hipStream_t stream) {
  const int*   inp   = (const int*)d_in[0];
  const float* emb0  = (const float*)d_in[1];
  const float* proj0 = (const float*)d_in[2];
  const float* emb1  = (const float*)d_in[3];
  const float* proj1 = (const float*)d_in[4];
  const float* emb2  = (const float*)d_in[5];
  const float* proj2 = (const float*)d_in[6];
  const float* emb3  = (const float*)d_in[7];
  const float* proj3 = (const float*)d_in[8];
  float* out = (float*)d_out;
  const int n = in_sizes[0];  // 16384 tokens

  int*      counts = (int*)d_ws;                 // 4 ints
  unsigned* lists  = (unsigned*)d_ws + 4;        // 4 x n packed entries

  hipMemsetAsync(counts, 0, 4 * sizeof(int), stream);
  classify_kernel<<<dim3((n + 255) / 256), dim3(256), 0, stream>>>(inp, n, counts, lists);
  zero_b0<<<dim3(256), dim3(256), 0, stream>>>(counts, lists, out);

  // y worst case: 4*ceil(n/64) (all tokens bucket 0) + 3; dead blocks exit on
  // a single counts read.
  dim3 grid(DPROJ / 128, 4 * ((n + 63) / 64) + 3, 1);
  size_t smem_bytes = 24576 + 64 * sizeof(unsigned);  // 24832 B -> 6 blocks/CU
  gemm_all<<<grid, dim3(256), smem_bytes, stream>>>(emb0, proj0, emb1, proj1,
                                                    emb2, proj2, emb3, proj3,
                                                    counts, lists, out, n);
}